// Round 4
// baseline (626.318 us; speedup 1.0000x reference)
//
#include <hip/hip_runtime.h>

#define K1 8192
#define F 256
#define BM 32
#define BK 64
#define NSTEP (K1 / BK)

typedef __attribute__((ext_vector_type(8))) short bf16x8;
typedef __attribute__((ext_vector_type(4))) float f32x4;

__device__ __forceinline__ unsigned short f2bf(float f) {
  union { float f; unsigned int u; } v; v.f = f;
  unsigned int u = v.u;
  u += 0x7fffu + ((u >> 16) & 1u);   // RNE
  return (unsigned short)(u >> 16);
}

__device__ __forceinline__ void gload_lds16(const void* g, void* l) {
  __builtin_amdgcn_global_load_lds((const __attribute__((address_space(1))) void*)g,
                                   (__attribute__((address_space(3))) void*)l,
                                   16, 0, 0);
}

// fp32 [R][C] -> bf16 [C][R]
__global__ __launch_bounds__(256) void transpose_cvt(const float* __restrict__ in,
                                                     unsigned short* __restrict__ outT,
                                                     int R, int C) {
  __shared__ float tile[32][33];
  const int r0 = blockIdx.x << 5, c0 = blockIdx.y << 5;
  const int t = threadIdx.x;
  const int rr = t >> 3, cc = (t & 7) << 2;
  float4 v = *(const float4*)(in + (size_t)(r0 + rr) * C + c0 + cc);
  tile[rr][cc + 0] = v.x; tile[rr][cc + 1] = v.y;
  tile[rr][cc + 2] = v.z; tile[rr][cc + 3] = v.w;
  __syncthreads();
  ushort4 o;
  o.x = f2bf(tile[cc + 0][rr]);
  o.y = f2bf(tile[cc + 1][rr]);
  o.z = f2bf(tile[cc + 2][rr]);
  o.w = f2bf(tile[cc + 3][rr]);
  *(ushort4*)(outT + (size_t)(c0 + rr) * R + r0 + cc) = o;
}

__global__ __launch_bounds__(512) void gat_main(
    const float* __restrict__ att, const int* __restrict__ adj,
    const unsigned short* __restrict__ Bt, const unsigned short* __restrict__ Wt,
    const float* __restrict__ bias, float* __restrict__ out) {

  __shared__ alignas(16) unsigned short ldsA[2][BM * BK];   //  8 KB
  __shared__ alignas(16) unsigned short ldsB[2][F * BK];    // 64 KB
  __shared__ alignas(16) unsigned short ldsX[BM * F];       // 16 KB

  const int tid = threadIdx.x;
  const int lane = tid & 63;
  const int w = tid >> 6;                 // wave 0..7
  const int rw = w & 1;                   // row-tile of 16
  const int colbase = (w >> 1) << 6;      // 64-col slab
  const int row0 = blockIdx.x * BM;

  // A staging coords: thread t handles row ar, 4-elem chunk ac4
  const int ar = tid >> 4;                // 0..31
  const int ac4 = tid & 15;               // 0..15
  const int awbyte = ar * 128 + (((ac4 >> 1) ^ (ar & 7)) << 4) + ((ac4 & 1) << 3);
  const size_t aoff = (size_t)(row0 + ar) * K1 + (ac4 << 2);

  f32x4 acc[4];
#pragma unroll
  for (int f = 0; f < 4; ++f) acc[f] = (f32x4){0.f, 0.f, 0.f, 0.f};

  // ---- prologue: stage K-tile 0 into buffer 0
  {
    float4 attv = *(const float4*)(att + aoff);
    int4 adjv = *(const int4*)(adj + aoff);
#pragma unroll
    for (int j = 0; j < 4; ++j) {
      const int byteoff = (j << 13) + (tid << 4);
      const int n = byteoff >> 7;                       // Bt row (col of B)
      const int k2 = ((byteoff >> 4) & 7) ^ (n & 7);    // pre-swizzled source chunk
      gload_lds16(Bt + ((size_t)n << 13) + (k2 << 3),
                  (char*)&ldsB[0][0] + (j << 13) + (w << 10));
    }
    ushort4 pk;
    pk.x = f2bf(adjv.x ? attv.x : 0.f);
    pk.y = f2bf(adjv.y ? attv.y : 0.f);
    pk.z = f2bf(adjv.z ? attv.z : 0.f);
    pk.w = f2bf(adjv.w ? attv.w : 0.f);
    *(ushort4*)((char*)&ldsA[0][0] + awbyte) = pk;
    __syncthreads();
  }

  int buf = 0;
  for (int t = 0; t < NSTEP; ++t) {
    const int nxt = buf ^ 1;
    const bool has_next = (t + 1 < NSTEP);
    float4 attv; int4 adjv;
    if (has_next) {
      const int kb = (t + 1) * BK;
      attv = *(const float4*)(att + aoff + kb);
      adjv = *(const int4*)(adj + aoff + kb);
#pragma unroll
      for (int j = 0; j < 4; ++j) {
        const int byteoff = (j << 13) + (tid << 4);
        const int n = byteoff >> 7;
        const int k2 = ((byteoff >> 4) & 7) ^ (n & 7);
        gload_lds16(Bt + ((size_t)n << 13) + kb + (k2 << 3),
                    (char*)&ldsB[nxt][0] + (j << 13) + (w << 10));
      }
    }
    // compute on current buffer: 2 k-slices x 4 col-tiles
#pragma unroll
    for (int s = 0; s < 2; ++s) {
      const int r = (rw << 4) + (lane & 15);
      const int k2a = (s << 2) + (lane >> 4);
      bf16x8 afrag = *(const bf16x8*)((char*)&ldsA[buf][0] + r * 128 + ((k2a ^ (r & 7)) << 4));
#pragma unroll
      for (int f = 0; f < 4; ++f) {
        const int n = colbase + (f << 4) + (lane & 15);
        bf16x8 bfrag = *(const bf16x8*)((char*)&ldsB[buf][0] + n * 128 +
                                        ((((s << 2) + (lane >> 4)) ^ (n & 7)) << 4));
        acc[f] = __builtin_amdgcn_mfma_f32_16x16x32_bf16(afrag, bfrag, acc[f], 0, 0, 0);
      }
    }
    if (has_next) {
      ushort4 pk;
      pk.x = f2bf(adjv.x ? attv.x : 0.f);
      pk.y = f2bf(adjv.y ? attv.y : 0.f);
      pk.z = f2bf(adjv.z ? attv.z : 0.f);
      pk.w = f2bf(adjv.w ? attv.w : 0.f);
      *(ushort4*)((char*)&ldsA[nxt][0] + awbyte) = pk;
    }
    __syncthreads();
    buf = nxt;
  }

  // ---- fused GEMM2: out = relu(x @ W + b), x-tile lives in acc
#pragma unroll
  for (int f = 0; f < 4; ++f) {
#pragma unroll
    for (int b = 0; b < 4; ++b) {
      const int r = (rw << 4) + ((lane >> 4) << 2) + b;
      const int c = colbase + (f << 4) + (lane & 15);
      const int byte = (r << 9) + ((((c >> 3) ^ (r & 7)) << 4)) + ((c & 7) << 1);
      *(unsigned short*)((char*)&ldsX[0] + byte) = f2bf(acc[f][b]);
    }
  }
  __syncthreads();

  f32x4 acc2[4];
#pragma unroll
  for (int f = 0; f < 4; ++f) {
    const float bv = bias[colbase + (f << 4) + (lane & 15)];
    acc2[f] = (f32x4){bv, bv, bv, bv};
  }
#pragma unroll
  for (int s2 = 0; s2 < 8; ++s2) {
    const int r = (rw << 4) + (lane & 15);
    const int kk = (s2 << 5) + ((lane >> 4) << 3);
    bf16x8 a2 = *(const bf16x8*)((char*)&ldsX[0] + (r << 9) + (((kk >> 3) ^ (r & 7)) << 4));
#pragma unroll
    for (int f = 0; f < 4; ++f) {
      const int n = colbase + (f << 4) + (lane & 15);
      bf16x8 w2 = *(const bf16x8*)(Wt + ((size_t)n << 8) + kk);
      acc2[f] = __builtin_amdgcn_mfma_f32_16x16x32_bf16(a2, w2, acc2[f], 0, 0, 0);
    }
  }
#pragma unroll
  for (int f = 0; f < 4; ++f) {
#pragma unroll
    for (int b = 0; b < 4; ++b) {
      const int r = row0 + (rw << 4) + ((lane >> 4) << 2) + b;
      const int c = colbase + (f << 4) + (lane & 15);
      out[(size_t)r * F + c] = fmaxf(acc2[f][b], 0.f);
    }
  }
}

extern "C" void kernel_launch(void* const* d_in, const int* in_sizes, int n_in,
                              void* d_out, int out_size, void* d_ws, size_t ws_size,
                              hipStream_t stream) {
  const int* adj = (const int*)d_in[0];
  const float* x_in = (const float*)d_in[1];
  const float* att = (const float*)d_in[2];
  const float* W = (const float*)d_in[3];
  const float* b = (const float*)d_in[4];
  float* out = (float*)d_out;

  unsigned short* Bt = (unsigned short*)d_ws;                                   // 256x8192 bf16, 4 MB
  unsigned short* Wt = (unsigned short*)((char*)d_ws + (size_t)256 * 8192 * 2); // 256x256 bf16

  dim3 g1(K1 / 32, F / 32);
  transpose_cvt<<<g1, 256, 0, stream>>>(x_in, Bt, K1, F);
  dim3 g2(F / 32, F / 32);
  transpose_cvt<<<g2, 256, 0, stream>>>(W, Wt, F, F);
  gat_main<<<K1 / BM, 512, 0, stream>>>(att, adj, Bt, Wt, b, out);
}